// Round 3
// baseline (183.367 us; speedup 1.0000x reference)
//
#include <hip/hip_runtime.h>

// SpikingLinearAttention forward — fully fused single kernel.
//  features = exp(X) @ W via 6-term bf16-split MFMA (f32-dot precision)
//  gate in f32, in-chunk cumsum IN REGISTERS (MFMA C/D layout), cross-chunk
//  prefix via deterministic full-walk decoupled lookback (8B agent atomics).

constexpr int cB = 32;
constexpr int cS = 8192;
constexpr int cD = 64;
constexpr int cF = 128;
constexpr int CHUNK = 64;
constexpr int NCH = cS / CHUNK;   // 128 chunks per batch
constexpr int SLOT = 520;         // ushorts per p-plane slot (1040 B = 260 dw ≡ 4 mod 32)
constexpr float EPS_ = 1e-8f;

typedef __attribute__((ext_vector_type(8))) short bf16x8;  // 8 bf16 (4 VGPRs)
typedef __attribute__((ext_vector_type(4))) float f32x4;   // 4 f32 acc

#define MFMA16(a, b, c) __builtin_amdgcn_mfma_f32_16x16x32_bf16((a), (b), (c), 0, 0, 0)

// ---- bf16 split helpers ----------------------------------------------------
__device__ __forceinline__ unsigned short bf16rn(float x) {
    unsigned u = __float_as_uint(x);
    unsigned r = u + 0x7FFFu + ((u >> 16) & 1u);
    return (unsigned short)(r >> 16);
}
__device__ __forceinline__ float bf16tof(unsigned short h) {
    return __uint_as_float((unsigned)h << 16);
}
__device__ __forceinline__ void split3(float x, unsigned short& a0,
                                       unsigned short& a1, unsigned short& a2) {
    a0 = bf16rn(x);
    float r1 = x - bf16tof(a0);
    a1 = bf16rn(r1);
    float r2 = r1 - bf16tof(a1);
    a2 = bf16rn(r2);
}

// A-frag: lane l holds A[l&15][(l>>4)*8+j].  B-frag: lane l holds B[(l>>4)*8+j][l&15].
// C/D: lane l, reg r -> row (l>>4)*4+r, col l&15.  [m89-verified, carried from passing R2]

// ---- K0: split W (64x128) into 3 bf16 matrices in B-frag order (global) ----
__global__ __launch_bounds__(256) void k_wsplit(const float* __restrict__ W,
                                                unsigned short* __restrict__ ws) {
    for (int i = threadIdx.x; i < cD * cF; i += 256) {
        int d = i >> 7, f = i & 127;
        unsigned short s0, s1, s2;
        split3(W[i], s0, s1, s2);
        int n = f >> 4, k = d >> 5;
        int lane = (f & 15) | (((d >> 3) & 3) << 4);
        int j = d & 7;
        int base = ((n * 2 + k) * 3) * 512 + lane * 8 + j;
        ws[base]        = s0;
        ws[base + 512]  = s1;
        ws[base + 1024] = s2;
    }
}

// ---- LDS staging: exp + split3 + frag-order write, XOR-swizzled ------------
// in-slot byte b0 = lane_frag*16 + jj*8 ; stored at b0 ^ (((b0>>8)&3)<<5).
__device__ __forceinline__ void stage_mat(const float4* __restrict__ src,
                                          unsigned short* __restrict__ af, int t) {
#pragma unroll
    for (int i = 0; i < 4; ++i) {
        int idx = t + i * 256;               // float4 index within 64x64
        int row = idx >> 4, c4 = (idx & 15) * 4;
        float4 a = src[idx];
        float e0 = __expf(a.x), e1 = __expf(a.y), e2 = __expf(a.z), e3 = __expf(a.w);
        unsigned short s0[4], s1[4], s2[4];
        split3(e0, s0[0], s1[0], s2[0]);
        split3(e1, s0[1], s1[1], s2[1]);
        split3(e2, s0[2], s1[2], s2[2]);
        split3(e3, s0[3], s1[3], s2[3]);
        int m = row >> 4, k = c4 >> 5;
        int lane_frag = (row & 15) | (((c4 >> 3) & 3) << 4);
        int jj = (c4 & 7) >> 2;
        int b0 = lane_frag * 16 + jj * 8;
        int byte = b0 ^ (((b0 >> 8) & 3) << 5);
        char* dst = (char*)af + (m * 2 + k) * 3 * (SLOT * 2) + byte;
        uint2 v0, v1, v2;
        v0.x = (unsigned)s0[0] | ((unsigned)s0[1] << 16);
        v0.y = (unsigned)s0[2] | ((unsigned)s0[3] << 16);
        v1.x = (unsigned)s1[0] | ((unsigned)s1[1] << 16);
        v1.y = (unsigned)s1[2] | ((unsigned)s1[3] << 16);
        v2.x = (unsigned)s2[0] | ((unsigned)s2[1] << 16);
        v2.y = (unsigned)s2[2] | ((unsigned)s2[3] << 16);
        *(uint2*)(dst)            = v0;
        *(uint2*)(dst + SLOT * 2) = v1;
        *(uint2*)(dst + SLOT * 4) = v2;
    }
}

__device__ __forceinline__ void read_frag(const unsigned short* __restrict__ af,
                                          int mk, int l, bf16x8* out3) {
    int b0 = l * 16;
    int byte = b0 ^ (((b0 >> 8) & 3) << 5);
    const char* p = (const char*)af + mk * 3 * (SLOT * 2) + byte;
    out3[0] = *(const bf16x8*)(p);
    out3[1] = *(const bf16x8*)(p + SLOT * 2);
    out3[2] = *(const bf16x8*)(p + SLOT * 4);
}

#define GEMM6(acc, A, Wf)            \
    acc = MFMA16(A[0], Wf[0], acc);  \
    acc = MFMA16(A[0], Wf[1], acc);  \
    acc = MFMA16(A[1], Wf[0], acc);  \
    acc = MFMA16(A[1], Wf[1], acc);  \
    acc = MFMA16(A[0], Wf[2], acc);  \
    acc = MFMA16(A[2], Wf[0], acc);

__device__ __forceinline__ unsigned long long agg_ld(const unsigned long long* p) {
    return __hip_atomic_load(p, __ATOMIC_RELAXED, __HIP_MEMORY_SCOPE_AGENT);
}

// ---- fused kernel ----------------------------------------------------------
__global__ __launch_bounds__(256, 2) void k_main(const float* __restrict__ Q,
                                                 const float* __restrict__ K,
                                                 const float* __restrict__ V,
                                                 const unsigned short* __restrict__ wsplit,
                                                 float* __restrict__ out,
                                                 unsigned long long* __restrict__ agg)
{
    __shared__ unsigned short afK[24 * SLOT];   // 24960 B (Q reuses this)
    __shared__ unsigned short afV[24 * SLOT];   // 24960 B
    __shared__ float prevK[cF], prevKv[cF];

    const int b = blockIdx.y, c = blockIdx.x;
    const int t = threadIdx.x, w = t >> 6, l = t & 63;
    const int col = l & 15, g = l >> 4;

    // B-frags for this wave's two n-tiles
    bf16x8 wf[2][2][3];
#pragma unroll
    for (int n = 0; n < 2; ++n)
#pragma unroll
        for (int k = 0; k < 2; ++k)
#pragma unroll
            for (int p = 0; p < 3; ++p) {
                int slot = ((2 * w + n) * 2 + k) * 3 + p;
                wf[n][k][p] = *(const bf16x8*)(wsplit + slot * 512 + l * 8);
            }

    const size_t rowbase = ((size_t)b * cS + (size_t)c * CHUNK) * cD;
    stage_mat((const float4*)(K + rowbase), afK, t);
    stage_mat((const float4*)(V + rowbase), afV, t);
    __syncthreads();

    // K and V feature GEMMs
    f32x4 accK[4][2] = {};
    f32x4 accV[4][2] = {};
#pragma unroll
    for (int m = 0; m < 4; ++m)
#pragma unroll
        for (int k = 0; k < 2; ++k) {
            bf16x8 aK[3], aV[3];
            read_frag(afK, m * 2 + k, l, aK);
            read_frag(afV, m * 2 + k, l, aV);
#pragma unroll
            for (int n = 0; n < 2; ++n) {
                GEMM6(accK[m][n], aK, wf[n][k]);
                GEMM6(accV[m][n], aV, wf[n][k]);
            }
        }

    // gate in f32; accK := k_s, accV := k_s * v_f
#pragma unroll
    for (int m = 0; m < 4; ++m)
#pragma unroll
        for (int n = 0; n < 2; ++n)
#pragma unroll
            for (int r = 0; r < 4; ++r) {
                float kf = accK[m][n][r];
                float ks = (kf > 0.5f) ? kf : 0.f;
                accK[m][n][r] = ks;
                accV[m][n][r] = ks * accV[m][n][r];
            }

    // in-register inclusive cumsum over s = m*16 + g*4 + r (per feature column)
    float ktot[2], kvtot[2];
#pragma unroll
    for (int n = 0; n < 2; ++n) {
        float cK = 0.f, cV = 0.f;
#pragma unroll
        for (int m = 0; m < 4; ++m) {
            f32x4 aK = accK[m][n], aV = accV[m][n];
            aK[1] += aK[0]; aK[2] += aK[1]; aK[3] += aK[2];
            aV[1] += aV[0]; aV[2] += aV[1]; aV[3] += aV[2];
            float tK = aK[3], tV = aV[3];
            float uK = __shfl_up(tK, 16), uV = __shfl_up(tV, 16);
            if (g >= 1) { tK += uK; tV += uV; }
            float xK = __shfl_up(tK, 32), xV = __shfl_up(tV, 32);
            if (g >= 2) { tK += xK; tV += xV; }
            float eK = tK - aK[3] + cK;        // exclusive group prefix + m-carry
            float eV = tV - aV[3] + cV;
            aK[0] += eK; aK[1] += eK; aK[2] += eK; aK[3] += eK;
            aV[0] += eV; aV[1] += eV; aV[2] += eV; aV[3] += eV;
            accK[m][n] = aK; accV[m][n] = aV;
            cK += __shfl(tK, 48 + col);        // m-tile total (group-3 inclusive)
            cV += __shfl(tV, 48 + col);
        }
        ktot[n] = cK; kvtot[n] = cV;
    }

    // publish chunk aggregates: one 8B atom per feature (flag = ks field != 0)
    if (g == 0) {
#pragma unroll
        for (int n = 0; n < 2; ++n) {
            int f = w * 32 + n * 16 + col;
            unsigned long long u = ((unsigned long long)__float_as_uint(kvtot[n]) << 32)
                                 | (unsigned long long)__float_as_uint(ktot[n] + 1.0f);
            __hip_atomic_store(agg + (size_t)(b * NCH + c) * cF + f, u,
                               __ATOMIC_RELAXED, __HIP_MEMORY_SCOPE_AGENT);
        }
    }

    __syncthreads();                       // all reads of afK done -> reuse for Q
    stage_mat((const float4*)(Q + rowbase), afK, t);
    __syncthreads();

    // Q feature GEMM
    f32x4 accQ[4][2] = {};
#pragma unroll
    for (int m = 0; m < 4; ++m)
#pragma unroll
        for (int k = 0; k < 2; ++k) {
            bf16x8 aQ[3];
            read_frag(afK, m * 2 + k, l, aQ);
#pragma unroll
            for (int n = 0; n < 2; ++n) {
                GEMM6(accQ[m][n], aQ, wf[n][k]);
            }
        }

    // deterministic full-walk lookback: thread t<128 owns feature f=t
    if (t < cF) {
        float aK0 = 0, aK1 = 0, aK2 = 0, aK3 = 0;
        float aV0 = 0, aV1 = 0, aV2 = 0, aV3 = 0;
        if (c > 0) {
            const unsigned long long* base = agg + (size_t)b * NCH * cF + t;
            int cc = c - 1;
            for (; cc >= 3; cc -= 4) {
                const unsigned long long* p0 = base + (size_t)cc * cF;
                const unsigned long long* p1 = base + (size_t)(cc - 1) * cF;
                const unsigned long long* p2 = base + (size_t)(cc - 2) * cF;
                const unsigned long long* p3 = base + (size_t)(cc - 3) * cF;
                unsigned long long v0 = agg_ld(p0), v1 = agg_ld(p1);
                unsigned long long v2 = agg_ld(p2), v3 = agg_ld(p3);
                while ((unsigned)v0 == 0u) v0 = agg_ld(p0);
                while ((unsigned)v1 == 0u) v1 = agg_ld(p1);
                while ((unsigned)v2 == 0u) v2 = agg_ld(p2);
                while ((unsigned)v3 == 0u) v3 = agg_ld(p3);
                aK0 += __uint_as_float((unsigned)v0) - 1.0f;
                aV0 += __uint_as_float((unsigned)(v0 >> 32));
                aK1 += __uint_as_float((unsigned)v1) - 1.0f;
                aV1 += __uint_as_float((unsigned)(v1 >> 32));
                aK2 += __uint_as_float((unsigned)v2) - 1.0f;
                aV2 += __uint_as_float((unsigned)(v2 >> 32));
                aK3 += __uint_as_float((unsigned)v3) - 1.0f;
                aV3 += __uint_as_float((unsigned)(v3 >> 32));
            }
            for (; cc >= 0; --cc) {
                const unsigned long long* p0 = base + (size_t)cc * cF;
                unsigned long long v0 = agg_ld(p0);
                while ((unsigned)v0 == 0u) v0 = agg_ld(p0);
                aK0 += __uint_as_float((unsigned)v0) - 1.0f;
                aV0 += __uint_as_float((unsigned)(v0 >> 32));
            }
        }
        prevK[t]  = (aK0 + aK1) + (aK2 + aK3);
        prevKv[t] = (aV0 + aV1) + (aV2 + aV3);
    }
    __syncthreads();

    // output: out[s][f] = q_s * (kv_cum + eps) / (k_cum + eps)
    const size_t obase = ((size_t)b * cS + (size_t)c * CHUNK) * cF;
#pragma unroll
    for (int n = 0; n < 2; ++n) {
        int f = w * 32 + n * 16 + col;
        float pK = prevK[f], pV = prevKv[f];
#pragma unroll
        for (int m = 0; m < 4; ++m)
#pragma unroll
            for (int r = 0; r < 4; ++r) {
                int s = m * 16 + g * 4 + r;
                float qf = accQ[m][n][r];
                float qs = (qf > 0.5f) ? qf : 0.f;
                float kc = accK[m][n][r] + pK;
                float vc = accV[m][n][r] + pV;
                float attn = __fdividef(vc + EPS_, kc + EPS_);
                out[obase + (size_t)s * cF + f] = qs * attn;
            }
    }
}

// ---------------------------------------------------------------------------
extern "C" void kernel_launch(void* const* d_in, const int* in_sizes, int n_in,
                              void* d_out, int out_size, void* d_ws, size_t ws_size,
                              hipStream_t stream) {
    const float* q = (const float*)d_in[0];
    const float* k = (const float*)d_in[1];
    const float* v = (const float*)d_in[2];
    const float* w = (const float*)d_in[3];
    float* out = (float*)d_out;

    unsigned short* wsplit = (unsigned short*)d_ws;                     // 48 KiB
    unsigned long long* agg = (unsigned long long*)((char*)d_ws + 65536); // 4 MiB

    hipMemsetAsync(agg, 0, (size_t)cB * NCH * cF * sizeof(unsigned long long), stream);
    k_wsplit<<<1, 256, 0, stream>>>(w, wsplit);
    k_main<<<dim3(NCH, cB), 256, 0, stream>>>(q, k, v, wsplit, out, agg);
}